// Round 9
// baseline (48.591 us; speedup 1.0000x reference)
//
#include <hip/hip_runtime.h>
#include <hip/hip_fp16.h>

#define DX 160
#define DY 192
#define DZ 160
#define PLANE (DY*DZ)
#define NVOX (DX*DY*DZ)

#define ZP   80            // z-pairs (z = 2*zp, 2*zp+1), full z-line
#define YC   4             // interior y rows per block
#define NYB  (DY/YC)       // 48
#define XC   10            // interior x slices per block
#define NXB  (DX/XC)       // 16
#define NS   (XC+4)        // 14 slices per block
#define ROWS (YC+4)        // 8 slab rows
#define NT   (YC*ZP)       // 320 threads = 5 waves
#define NBLK (NXB*NYB)     // 768 blocks = 3/CU exactly
#define RAWSLOTS (ROWS*DZ) // 1280 float2 slots = exactly 4*NT

__device__ __forceinline__ int iclamp(int v, int hi) {
    return v < 0 ? 0 : (v > hi ? hi : v);
}

__device__ __forceinline__ __half2 h2(int v) {
    return __builtin_bit_cast(__half2, v);
}

// ---------------------------------------------------------------------------
// Fully fused LCC, small-block edition.
// R5-R8 post-mortem: occupancy pinned at ~24% (= one 640-thread block/CU)
// in EVERY variant because LDS/block was always >32 KB; with an effective
// ~64 KB co-residency budget, 2 blocks never fit. All barrier/pipeline/grid
// changes were null because resident-wave count never moved.
// This round: 320-thread blocks (5 waves), LDS 18.7 KB -> >=3 blocks/CU with
// INDEPENDENT barriers; grid 768 = 3/CU exactly (no tail). R5 loop structure
// (2 barriers/slice, register prefetch of slice i+1). Finalize folded in via
// deterministic last-block reduction (fixed-order sum -> bit-reproducible).
// ---------------------------------------------------------------------------
__global__ __launch_bounds__(NT, 4) void lcc_fused(const float* __restrict__ F,
                                                   const float* __restrict__ M,
                                                   float* __restrict__ partials,
                                                   unsigned* __restrict__ counter,
                                                   float* __restrict__ out) {
    __shared__ float4   rawS[ROWS * ZP];  // (f(z0),m(z0),f(z1),m(z1)) : 10240 B
    __shared__ int4     ybA[YC * ZP];     // half2(q0,q1)|half2(q2,q3) :  5120 B
    __shared__ unsigned ybB[YC * ZP];     // half2(q4_z0, q4_z1)       :  1280 B
    __shared__ float    red[512];         //                            2048 B
    __shared__ unsigned lastFlag;         // total ~18.7 KB

    const int tid = threadIdx.x;
    const int zp  = tid % ZP;
    const int ty  = tid / ZP;
    const int y0  = blockIdx.y * YC;
    const int x0  = blockIdx.x * XC;
    const int bid = blockIdx.y * NXB + blockIdx.x;

    // hoisted staging offsets (4 float2 slots per thread, exact cover)
    int soff[4];
    #pragma unroll
    for (int k = 0; k < 4; ++k) {
        const int e   = tid + k * NT;
        const int row = e / DZ, zz = e % DZ;
        soff[k] = iclamp(y0 + row - 2, DY - 1) * DZ + zz;
    }

    // ---- stage slice 0 ----
    {
        const int xx = iclamp(x0 - 2, DX - 1);
        const float* fp = F + (size_t)xx * PLANE;
        const float* mp = M + (size_t)xx * PLANE;
        #pragma unroll
        for (int k = 0; k < 4; ++k)
            ((float2*)rawS)[tid + k * NT] = make_float2(fp[soff[k]], mp[soff[k]]);
    }
    __syncthreads();

    float acc = 0.f;
    float sA[5], sB[5];
    unsigned hp[4][5];          // history: half2(SA[q], SB[q]) per step
    #pragma unroll
    for (int q = 0; q < 5; ++q) { sA[q] = 0.f; sB[q] = 0.f; }
    #pragma unroll
    for (int k = 0; k < 4; ++k)
        #pragma unroll
        for (int q = 0; q < 5; ++q) hp[k][q] = 0u;

    for (int i = 0; i < NS; ++i) {
        // ---- stage1: y-box (5 row taps) in f32 registers ----
        float yA[5] = {0,0,0,0,0};  // q: f, m, fm, ff, mm  @ z0
        float yB[5] = {0,0,0,0,0};  //                      @ z1
        #pragma unroll
        for (int k = 0; k < 5; ++k) {
            const float4 t = rawS[(ty + k) * ZP + zp];
            yA[0] += t.x; yA[1] += t.y;
            yA[2] = fmaf(t.x, t.y, yA[2]);
            yA[3] = fmaf(t.x, t.x, yA[3]);
            yA[4] = fmaf(t.y, t.y, yA[4]);
            yB[0] += t.z; yB[1] += t.w;
            yB[2] = fmaf(t.z, t.w, yB[2]);
            yB[3] = fmaf(t.z, t.z, yB[3]);
            yB[4] = fmaf(t.w, t.w, yB[4]);
        }
        // ---- pack Y -> fp16 ybuf ----
        int4 w;
        w.x = __builtin_bit_cast(int, __floats2half2_rn(yA[0], yA[1]));
        w.y = __builtin_bit_cast(int, __floats2half2_rn(yA[2], yA[3]));
        w.z = __builtin_bit_cast(int, __floats2half2_rn(yB[0], yB[1]));
        w.w = __builtin_bit_cast(int, __floats2half2_rn(yB[2], yB[3]));
        ybA[ty * ZP + zp] = w;
        ybB[ty * ZP + zp] = __builtin_bit_cast(unsigned, __floats2half2_rn(yA[4], yB[4]));

        // ---- prefetch slice i+1 into regs (latency hides under stage2) ----
        float pf[4], pm[4];
        if (i + 1 < NS) {
            const int xx = iclamp(x0 + (i + 1) - 2, DX - 1);
            const float* fp = F + (size_t)xx * PLANE;
            const float* mp = M + (size_t)xx * PLANE;
            #pragma unroll
            for (int k = 0; k < 4; ++k) { pf[k] = fp[soff[k]]; pm[k] = mp[soff[k]]; }
        }

        __syncthreads();   // ybuf visible; all rawS reads of slice i done

        // ---- stage2: z-box over pairs (taps z0-2 .. z0+3) ----
        const int base = ty * ZP;
        int4 p0 = ybA[base + (zp == 0      ? 0      : zp - 1)];
        int4 p1 = ybA[base + zp];
        int4 p2 = ybA[base + (zp == ZP - 1 ? ZP - 1 : zp + 1)];
        unsigned b0 = ybB[base + (zp == 0      ? 0      : zp - 1)];
        unsigned b2 = ybB[base + (zp == ZP - 1 ? ZP - 1 : zp + 1)];
        const unsigned b1 = ybB[base + zp];
        if (zp == 0)      { p0.z = p0.x; p0.w = p0.y; b0 = (b0 & 0xffffu) | (b0 << 16); }
        if (zp == ZP - 1) { p2.x = p2.z; p2.y = p2.w; b2 = (b2 >> 16) | (b2 & 0xffff0000u); }

        // packed 5-tap sums: T = common 4 taps; Sz0 = T + low tap; Sz1 = T + high tap
        const __half2 t0  = __hadd2(__hadd2(h2(p0.z), h2(p1.x)), __hadd2(h2(p1.z), h2(p2.x)));
        const __half2 A01 = __hadd2(t0, h2(p0.x));
        const __half2 B01 = __hadd2(t0, h2(p2.z));
        const __half2 t1  = __hadd2(__hadd2(h2(p0.w), h2(p1.y)), __hadd2(h2(p1.w), h2(p2.y)));
        const __half2 A23 = __hadd2(t1, h2(p0.y));
        const __half2 B23 = __hadd2(t1, h2(p2.w));
        const __half2 c0 = h2((int)b0), c1 = h2((int)b1), c2 = h2((int)b2);
        const float tb = __high2float(c0) + __low2float(c1) + __high2float(c1) + __low2float(c2);
        const float SA[5] = { __low2float(A01), __high2float(A01),
                              __low2float(A23), __high2float(A23),
                              tb + __low2float(c0) };
        const float SB[5] = { __low2float(B01), __high2float(B01),
                              __low2float(B23), __high2float(B23),
                              tb + __high2float(c2) };

        // ---- x running window + LCC ----
        #pragma unroll
        for (int q = 0; q < 5; ++q) { sA[q] += SA[q]; sB[q] += SB[q]; }
        if (i >= 4) {
            const float inv = 1.0f / 125.0f;
            {
                const float cross = sA[2] - sA[0] * sA[1] * inv;
                const float fvar  = sA[3] - sA[0] * sA[0] * inv;
                const float mvar  = sA[4] - sA[1] * sA[1] * inv;
                acc += cross * cross / (fvar * mvar + 0.1f);
            }
            {
                const float cross = sB[2] - sB[0] * sB[1] * inv;
                const float fvar  = sB[3] - sB[0] * sB[0] * inv;
                const float mvar  = sB[4] - sB[1] * sB[1] * inv;
                acc += cross * cross / (fvar * mvar + 0.1f);
            }
            #pragma unroll
            for (int q = 0; q < 5; ++q) {
                const __half2 v = h2((int)hp[0][q]);
                sA[q] -= __low2float(v);
                sB[q] -= __high2float(v);
            }
        }
        #pragma unroll
        for (int k = 0; k < 3; ++k)
            #pragma unroll
            for (int q = 0; q < 5; ++q) hp[k][q] = hp[k + 1][q];
        #pragma unroll
        for (int q = 0; q < 5; ++q)
            hp[3][q] = __builtin_bit_cast(unsigned, __floats2half2_rn(SA[q], SB[q]));

        // ---- write prefetched slice i+1 into rawS ----
        if (i + 1 < NS) {
            #pragma unroll
            for (int k = 0; k < 4; ++k)
                ((float2*)rawS)[tid + k * NT] = make_float2(pf[k], pm[k]);
            __syncthreads();   // rawS ready; ybuf reads done
        }
    }

    // ---- block reduction (deterministic tree over 512 padded slots) ----
    red[tid] = acc;
    if (tid < 512 - NT) red[NT + tid] = 0.f;
    __syncthreads();
    #pragma unroll
    for (int st = 256; st > 0; st >>= 1) {
        if (tid < st) red[tid] += red[tid + st];
        __syncthreads();
    }

    // ---- last-block deterministic finalize (fixed-order sum of partials) ----
    if (tid == 0) {
        partials[bid] = red[0];
        __threadfence();                         // publish before ticket
        lastFlag = (atomicAdd(counter, 1u) == NBLK - 1) ? 1u : 0u;
    }
    __syncthreads();
    if (lastFlag) {
        __threadfence();                         // acquire all partials
        float a = 0.f;
        for (int i = tid; i < NBLK; i += NT) a += partials[i];
        red[tid] = a;
        if (tid < 512 - NT) red[NT + tid] = 0.f;
        __syncthreads();
        #pragma unroll
        for (int st = 256; st > 0; st >>= 1) {
            if (tid < st) red[tid] += red[tid + st];
            __syncthreads();
        }
        if (tid == 0) out[0] = -red[0];
    }
}

// ---------------------------------------------------------------------------
// Final deterministic reduction (fallback path only).
// ---------------------------------------------------------------------------
__global__ __launch_bounds__(256) void lcc_finalize(const float* __restrict__ partials,
                                                    int n, float* __restrict__ out) {
    __shared__ float red[256];
    float a = 0.f;
    for (int i = threadIdx.x; i < n; i += 256) a += partials[i];
    red[threadIdx.x] = a;
    __syncthreads();
    #pragma unroll
    for (int st = 128; st > 0; st >>= 1) {
        if (threadIdx.x < st) red[threadIdx.x] += red[threadIdx.x + st];
        __syncthreads();
    }
    if (threadIdx.x == 0) out[0] = -red[0];
}

// ---------------------------------------------------------------------------
// Fallback: direct 125-tap (only if ws is tiny).
// ---------------------------------------------------------------------------
__global__ __launch_bounds__(256) void lcc_direct(const float* __restrict__ f,
                                                  const float* __restrict__ m,
                                                  float* __restrict__ partials) {
    float acc = 0.f;
    for (int idx = blockIdx.x * 256 + threadIdx.x; idx < NVOX; idx += 256 * gridDim.x) {
        const int z = idx % DZ;
        const int y = (idx / DZ) % DY;
        const int x = idx / PLANE;
        float sf = 0, sm = 0, sfm = 0, sff = 0, smm = 0;
        for (int dx = -2; dx <= 2; ++dx) {
            const int xx = iclamp(x + dx, DX - 1);
            for (int dy = -2; dy <= 2; ++dy) {
                const int yy = iclamp(y + dy, DY - 1);
                const size_t b = (size_t)xx * PLANE + (size_t)yy * DZ;
                #pragma unroll
                for (int dz = -2; dz <= 2; ++dz) {
                    const int zz = iclamp(z + dz, DZ - 1);
                    const float fv = f[b + zz], mv = m[b + zz];
                    sf += fv; sm += mv; sfm += fv * mv; sff += fv * fv; smm += mv * mv;
                }
            }
        }
        const float inv = 1.0f / 125.0f;
        const float cross = sfm - sf * sm * inv;
        const float fvar  = sff - sf * sf * inv;
        const float mvar  = smm - sm * sm * inv;
        acc += cross * cross / (fvar * mvar + 0.1f);
    }
    __shared__ float red[256];
    red[threadIdx.x] = acc;
    __syncthreads();
    #pragma unroll
    for (int st = 128; st > 0; st >>= 1) {
        if (threadIdx.x < st) red[threadIdx.x] += red[threadIdx.x + st];
        __syncthreads();
    }
    if (threadIdx.x == 0) partials[blockIdx.x] = red[0];
}

extern "C" void kernel_launch(void* const* d_in, const int* in_sizes, int n_in,
                              void* d_out, int out_size, void* d_ws, size_t ws_size,
                              hipStream_t stream) {
    const float* f = (const float*)d_in[0];
    const float* m = (const float*)d_in[1];
    float* out = (float*)d_out;

    if (ws_size >= (NBLK + 1) * sizeof(float)) {
        float* partials = (float*)d_ws;
        unsigned* counter = (unsigned*)(partials + NBLK);
        hipMemsetAsync(counter, 0, sizeof(unsigned), stream);   // legal capture node
        lcc_fused<<<dim3(NXB, NYB), NT, 0, stream>>>(f, m, partials, counter, out);
    } else {
        const int nb = 512;
        float* partials = (float*)d_ws;
        lcc_direct<<<nb, 256, 0, stream>>>(f, m, partials);
        lcc_finalize<<<1, 256, 0, stream>>>(partials, nb, out);
    }
}

// Round 10
// 29.176 us; speedup vs baseline: 1.6654x; 1.6654x over previous
//
#include <hip/hip_runtime.h>
#include <hip/hip_fp16.h>

#define DX 160
#define DY 192
#define DZ 160
#define PLANE (DY*DZ)
#define NVOX (DX*DY*DZ)

#define ZP   80            // z-pairs (z = 2*zp, 2*zp+1), full z-line
#define YC   4             // interior y rows per block
#define NYB  (DY/YC)       // 48
#define XC   10            // interior x slices per block
#define NXB  (DX/XC)       // 16
#define NS   (XC+4)        // 14 slices per block
#define ROWS (YC+4)        // 8 slab rows
#define NT   (YC*ZP)       // 320 threads = 5 waves
#define NBLK (NXB*NYB)     // 768 blocks = 3/CU exactly
#define RAWSLOTS (ROWS*DZ) // 1280 float2 slots = exactly 4*NT

__device__ __forceinline__ int iclamp(int v, int hi) {
    return v < 0 ? 0 : (v > hi ? hi : v);
}

__device__ __forceinline__ __half2 h2(int v) {
    return __builtin_bit_cast(__half2, v);
}

// ---------------------------------------------------------------------------
// Fully fused LCC, small-block edition, de-confounded from R9:
//  - KEEP: 320-thread blocks (5 waves), LDS 18.7 KB, grid 768 = 3 blocks/CU
//    (R9's FETCH drop to 26 MB shows the better L2 tiling was real).
//  - REVERT: in-kernel last-block finalize. Its 768 device-scope
//    __threadfence()s = per-block L2 writebacks (cross-XCD coherence) were
//    the +15 us regression. Separate finalize kernel is ~2 us.
//  - NEW: global prefetch issued at TOP of slice loop (before stage1), so
//    stage1's ~300 cyc of LDS/VALU work covers load latency in addition to
//    stage2 (~700 cyc total cover vs ~400 before).
// ---------------------------------------------------------------------------
__global__ __launch_bounds__(NT, 4) void lcc_fused(const float* __restrict__ F,
                                                   const float* __restrict__ M,
                                                   float* __restrict__ partials) {
    __shared__ float4   rawS[ROWS * ZP];  // (f(z0),m(z0),f(z1),m(z1)) : 10240 B
    __shared__ int4     ybA[YC * ZP];     // half2(q0,q1)|half2(q2,q3) :  5120 B
    __shared__ unsigned ybB[YC * ZP];     // half2(q4_z0, q4_z1)       :  1280 B
    __shared__ float    red[512];         //                             2048 B

    const int tid = threadIdx.x;
    const int zp  = tid % ZP;
    const int ty  = tid / ZP;
    const int y0  = blockIdx.y * YC;
    const int x0  = blockIdx.x * XC;

    // hoisted staging offsets (4 float2 slots per thread, exact cover)
    int soff[4];
    #pragma unroll
    for (int k = 0; k < 4; ++k) {
        const int e   = tid + k * NT;
        const int row = e / DZ, zz = e % DZ;
        soff[k] = iclamp(y0 + row - 2, DY - 1) * DZ + zz;
    }

    // ---- stage slice 0 ----
    {
        const int xx = iclamp(x0 - 2, DX - 1);
        const float* fp = F + (size_t)xx * PLANE;
        const float* mp = M + (size_t)xx * PLANE;
        #pragma unroll
        for (int k = 0; k < 4; ++k)
            ((float2*)rawS)[tid + k * NT] = make_float2(fp[soff[k]], mp[soff[k]]);
    }
    __syncthreads();

    float acc = 0.f;
    float sA[5], sB[5];
    unsigned hp[4][5];          // history: half2(SA[q], SB[q]) per step
    #pragma unroll
    for (int q = 0; q < 5; ++q) { sA[q] = 0.f; sB[q] = 0.f; }
    #pragma unroll
    for (int k = 0; k < 4; ++k)
        #pragma unroll
        for (int q = 0; q < 5; ++q) hp[k][q] = 0u;

    for (int i = 0; i < NS; ++i) {
        // ---- prefetch slice i+1 FIRST: max latency cover (stage1+stage2) ----
        float pf[4], pm[4];
        if (i + 1 < NS) {
            const int xx = iclamp(x0 + (i + 1) - 2, DX - 1);
            const float* fp = F + (size_t)xx * PLANE;
            const float* mp = M + (size_t)xx * PLANE;
            #pragma unroll
            for (int k = 0; k < 4; ++k) { pf[k] = fp[soff[k]]; pm[k] = mp[soff[k]]; }
        }

        // ---- stage1: y-box (5 row taps) in f32 registers ----
        float yA[5] = {0,0,0,0,0};  // q: f, m, fm, ff, mm  @ z0
        float yB[5] = {0,0,0,0,0};  //                      @ z1
        #pragma unroll
        for (int k = 0; k < 5; ++k) {
            const float4 t = rawS[(ty + k) * ZP + zp];
            yA[0] += t.x; yA[1] += t.y;
            yA[2] = fmaf(t.x, t.y, yA[2]);
            yA[3] = fmaf(t.x, t.x, yA[3]);
            yA[4] = fmaf(t.y, t.y, yA[4]);
            yB[0] += t.z; yB[1] += t.w;
            yB[2] = fmaf(t.z, t.w, yB[2]);
            yB[3] = fmaf(t.z, t.z, yB[3]);
            yB[4] = fmaf(t.w, t.w, yB[4]);
        }
        // ---- pack Y -> fp16 ybuf ----
        int4 w;
        w.x = __builtin_bit_cast(int, __floats2half2_rn(yA[0], yA[1]));
        w.y = __builtin_bit_cast(int, __floats2half2_rn(yA[2], yA[3]));
        w.z = __builtin_bit_cast(int, __floats2half2_rn(yB[0], yB[1]));
        w.w = __builtin_bit_cast(int, __floats2half2_rn(yB[2], yB[3]));
        ybA[ty * ZP + zp] = w;
        ybB[ty * ZP + zp] = __builtin_bit_cast(unsigned, __floats2half2_rn(yA[4], yB[4]));

        __syncthreads();   // ybuf visible; all rawS reads of slice i done

        // ---- stage2: z-box over pairs (taps z0-2 .. z0+3) ----
        const int base = ty * ZP;
        int4 p0 = ybA[base + (zp == 0      ? 0      : zp - 1)];
        int4 p1 = ybA[base + zp];
        int4 p2 = ybA[base + (zp == ZP - 1 ? ZP - 1 : zp + 1)];
        unsigned b0 = ybB[base + (zp == 0      ? 0      : zp - 1)];
        unsigned b2 = ybB[base + (zp == ZP - 1 ? ZP - 1 : zp + 1)];
        const unsigned b1 = ybB[base + zp];
        if (zp == 0)      { p0.z = p0.x; p0.w = p0.y; b0 = (b0 & 0xffffu) | (b0 << 16); }
        if (zp == ZP - 1) { p2.x = p2.z; p2.y = p2.w; b2 = (b2 >> 16) | (b2 & 0xffff0000u); }

        // packed 5-tap sums: T = common 4 taps; Sz0 = T + low tap; Sz1 = T + high tap
        const __half2 t0  = __hadd2(__hadd2(h2(p0.z), h2(p1.x)), __hadd2(h2(p1.z), h2(p2.x)));
        const __half2 A01 = __hadd2(t0, h2(p0.x));
        const __half2 B01 = __hadd2(t0, h2(p2.z));
        const __half2 t1  = __hadd2(__hadd2(h2(p0.w), h2(p1.y)), __hadd2(h2(p1.w), h2(p2.y)));
        const __half2 A23 = __hadd2(t1, h2(p0.y));
        const __half2 B23 = __hadd2(t1, h2(p2.w));
        const __half2 c0 = h2((int)b0), c1 = h2((int)b1), c2 = h2((int)b2);
        const float tb = __high2float(c0) + __low2float(c1) + __high2float(c1) + __low2float(c2);
        const float SA[5] = { __low2float(A01), __high2float(A01),
                              __low2float(A23), __high2float(A23),
                              tb + __low2float(c0) };
        const float SB[5] = { __low2float(B01), __high2float(B01),
                              __low2float(B23), __high2float(B23),
                              tb + __high2float(c2) };

        // ---- x running window + LCC ----
        #pragma unroll
        for (int q = 0; q < 5; ++q) { sA[q] += SA[q]; sB[q] += SB[q]; }
        if (i >= 4) {
            const float inv = 1.0f / 125.0f;
            {
                const float cross = sA[2] - sA[0] * sA[1] * inv;
                const float fvar  = sA[3] - sA[0] * sA[0] * inv;
                const float mvar  = sA[4] - sA[1] * sA[1] * inv;
                acc += cross * cross / (fvar * mvar + 0.1f);
            }
            {
                const float cross = sB[2] - sB[0] * sB[1] * inv;
                const float fvar  = sB[3] - sB[0] * sB[0] * inv;
                const float mvar  = sB[4] - sB[1] * sB[1] * inv;
                acc += cross * cross / (fvar * mvar + 0.1f);
            }
            #pragma unroll
            for (int q = 0; q < 5; ++q) {
                const __half2 v = h2((int)hp[0][q]);
                sA[q] -= __low2float(v);
                sB[q] -= __high2float(v);
            }
        }
        #pragma unroll
        for (int k = 0; k < 3; ++k)
            #pragma unroll
            for (int q = 0; q < 5; ++q) hp[k][q] = hp[k + 1][q];
        #pragma unroll
        for (int q = 0; q < 5; ++q)
            hp[3][q] = __builtin_bit_cast(unsigned, __floats2half2_rn(SA[q], SB[q]));

        // ---- write prefetched slice i+1 into rawS ----
        if (i + 1 < NS) {
            #pragma unroll
            for (int k = 0; k < 4; ++k)
                ((float2*)rawS)[tid + k * NT] = make_float2(pf[k], pm[k]);
            __syncthreads();   // rawS ready; ybuf reads done
        }
    }

    // ---- block reduction (deterministic tree over 512 padded slots) ----
    red[tid] = acc;
    if (tid < 512 - NT) red[NT + tid] = 0.f;
    __syncthreads();
    #pragma unroll
    for (int st = 256; st > 0; st >>= 1) {
        if (tid < st) red[tid] += red[tid + st];
        __syncthreads();
    }
    if (tid == 0) partials[blockIdx.y * NXB + blockIdx.x] = red[0];
}

// ---------------------------------------------------------------------------
// Final deterministic reduction, writes -sum.
// ---------------------------------------------------------------------------
__global__ __launch_bounds__(256) void lcc_finalize(const float* __restrict__ partials,
                                                    int n, float* __restrict__ out) {
    __shared__ float red[256];
    float a = 0.f;
    for (int i = threadIdx.x; i < n; i += 256) a += partials[i];
    red[threadIdx.x] = a;
    __syncthreads();
    #pragma unroll
    for (int st = 128; st > 0; st >>= 1) {
        if (threadIdx.x < st) red[threadIdx.x] += red[threadIdx.x + st];
        __syncthreads();
    }
    if (threadIdx.x == 0) out[0] = -red[0];
}

// ---------------------------------------------------------------------------
// Fallback: direct 125-tap (only if ws is tiny).
// ---------------------------------------------------------------------------
__global__ __launch_bounds__(256) void lcc_direct(const float* __restrict__ f,
                                                  const float* __restrict__ m,
                                                  float* __restrict__ partials) {
    float acc = 0.f;
    for (int idx = blockIdx.x * 256 + threadIdx.x; idx < NVOX; idx += 256 * gridDim.x) {
        const int z = idx % DZ;
        const int y = (idx / DZ) % DY;
        const int x = idx / PLANE;
        float sf = 0, sm = 0, sfm = 0, sff = 0, smm = 0;
        for (int dx = -2; dx <= 2; ++dx) {
            const int xx = iclamp(x + dx, DX - 1);
            for (int dy = -2; dy <= 2; ++dy) {
                const int yy = iclamp(y + dy, DY - 1);
                const size_t b = (size_t)xx * PLANE + (size_t)yy * DZ;
                #pragma unroll
                for (int dz = -2; dz <= 2; ++dz) {
                    const int zz = iclamp(z + dz, DZ - 1);
                    const float fv = f[b + zz], mv = m[b + zz];
                    sf += fv; sm += mv; sfm += fv * mv; sff += fv * fv; smm += mv * mv;
                }
            }
        }
        const float inv = 1.0f / 125.0f;
        const float cross = sfm - sf * sm * inv;
        const float fvar  = sff - sf * sf * inv;
        const float mvar  = smm - sm * sm * inv;
        acc += cross * cross / (fvar * mvar + 0.1f);
    }
    __shared__ float red[256];
    red[threadIdx.x] = acc;
    __syncthreads();
    #pragma unroll
    for (int st = 128; st > 0; st >>= 1) {
        if (threadIdx.x < st) red[threadIdx.x] += red[threadIdx.x + st];
        __syncthreads();
    }
    if (threadIdx.x == 0) partials[blockIdx.x] = red[0];
}

extern "C" void kernel_launch(void* const* d_in, const int* in_sizes, int n_in,
                              void* d_out, int out_size, void* d_ws, size_t ws_size,
                              hipStream_t stream) {
    const float* f = (const float*)d_in[0];
    const float* m = (const float*)d_in[1];
    float* out = (float*)d_out;

    if (ws_size >= NBLK * sizeof(float)) {
        float* partials = (float*)d_ws;
        lcc_fused<<<dim3(NXB, NYB), NT, 0, stream>>>(f, m, partials);
        lcc_finalize<<<1, 256, 0, stream>>>(partials, NBLK, out);
    } else {
        const int nb = 512;
        float* partials = (float*)d_ws;
        lcc_direct<<<nb, 256, 0, stream>>>(f, m, partials);
        lcc_finalize<<<1, 256, 0, stream>>>(partials, nb, out);
    }
}

// Round 11
// 28.409 us; speedup vs baseline: 1.7104x; 1.0270x over previous
//
#include <hip/hip_runtime.h>
#include <hip/hip_fp16.h>

#define DX 160
#define DY 192
#define DZ 160
#define PLANE (DY*DZ)
#define NVOX (DX*DY*DZ)

#define ZP   80            // z-pairs (z = 2*zp, 2*zp+1), full z-line
#define YC   4             // interior y rows per block
#define NYB  (DY/YC)       // 48
#define XC   10            // interior x slices per block
#define NXB  (DX/XC)       // 16
#define NS   (XC+4)        // 14 slices per block (even: 7 pair-iterations)
#define NPAIR (NS/2)       // 7
#define ROWS (YC+4)        // 8 slab rows
#define NT   (YC*ZP)       // 320 threads = 5 waves
#define NBLK (NXB*NYB)     // 768 blocks = 3/CU exactly
#define RAWSLOTS (ROWS*DZ) // 1280 float2 slots = exactly 4*NT

__device__ __forceinline__ int iclamp(int v, int hi) {
    return v < 0 ? 0 : (v > hi ? hi : v);
}

__device__ __forceinline__ __half2 h2(int v) {
    return __builtin_bit_cast(__half2, v);
}

// ---------------------------------------------------------------------------
// Fully fused LCC, slice-PAIRED edition.
// R10 post-mortem: 25 us kernel with only ~6 us of VALU work (VALUBusy 24%).
// Stalls are correlated: all 5 waves of a block serialize on 2 barriers and
// one LDS-latency chain per slice, x14 slices. Neither fewer barriers alone
// (R6, 1 blk/CU) nor more blocks alone (R7/R10) helped. This round doubles
// the independent work inside each barrier region: slices 2t and 2t+1 are
// processed together with static dual LDS buffers --
//   issue loads(2t+2 -> regsA, 2t+3 -> regsB)        (cover ~2000 cyc)
//   stage1(rawS[0]->ybuf[0]); stage1(rawS[1]->ybuf[1])   (2x ILP)
//   barrier
//   stage2+xwindow(2t); stage2+xwindow(2t+1)             (2x ILP)
//   write regsA->rawS[0], regsB->rawS[1]
//   barrier
// = 1 barrier/slice and two independent latency chains per region.
// LDS 35.3 KB -> 3 blocks/CU at grid 768. Tail: wave-shuffle reduction
// (1 barrier instead of 9).
// ---------------------------------------------------------------------------
__global__ __launch_bounds__(NT, 4) void lcc_fused(const float* __restrict__ F,
                                                   const float* __restrict__ M,
                                                   float* __restrict__ partials) {
    __shared__ float4   rawS[2][ROWS * ZP];  // 2 x 10240 B
    __shared__ int4     ybA[2][YC * ZP];     // 2 x  5120 B
    __shared__ unsigned ybB[2][YC * ZP];     // 2 x  1280 B
    __shared__ float    wred[8];             // total ~35.3 KB

    const int tid = threadIdx.x;
    const int zp  = tid % ZP;
    const int ty  = tid / ZP;
    const int y0  = blockIdx.y * YC;
    const int x0  = blockIdx.x * XC;

    // hoisted staging offsets (4 float2 slots per thread, exact cover)
    int soff[4];
    #pragma unroll
    for (int k = 0; k < 4; ++k) {
        const int e   = tid + k * NT;
        const int row = e / DZ, zz = e % DZ;
        soff[k] = iclamp(y0 + row - 2, DY - 1) * DZ + zz;
    }

    auto issueR = [&](int j, float (&pf)[4], float (&pm)[4]) {
        const int xx = iclamp(x0 + j - 2, DX - 1);
        const float* fp = F + (size_t)xx * PLANE;
        const float* mp = M + (size_t)xx * PLANE;
        #pragma unroll
        for (int k = 0; k < 4; ++k) { pf[k] = fp[soff[k]]; pm[k] = mp[soff[k]]; }
    };
    auto writeW = [&](int buf, const float (&pf)[4], const float (&pm)[4]) {
        #pragma unroll
        for (int k = 0; k < 4; ++k)
            ((float2*)rawS[buf])[tid + k * NT] = make_float2(pf[k], pm[k]);
    };
    auto stage1 = [&](int buf) {   // reads rawS[buf], writes ybuf[buf]
        float yA[5] = {0,0,0,0,0};
        float yB[5] = {0,0,0,0,0};
        #pragma unroll
        for (int k = 0; k < 5; ++k) {
            const float4 t = rawS[buf][(ty + k) * ZP + zp];
            yA[0] += t.x; yA[1] += t.y;
            yA[2] = fmaf(t.x, t.y, yA[2]);
            yA[3] = fmaf(t.x, t.x, yA[3]);
            yA[4] = fmaf(t.y, t.y, yA[4]);
            yB[0] += t.z; yB[1] += t.w;
            yB[2] = fmaf(t.z, t.w, yB[2]);
            yB[3] = fmaf(t.z, t.z, yB[3]);
            yB[4] = fmaf(t.w, t.w, yB[4]);
        }
        int4 w;
        w.x = __builtin_bit_cast(int, __floats2half2_rn(yA[0], yA[1]));
        w.y = __builtin_bit_cast(int, __floats2half2_rn(yA[2], yA[3]));
        w.z = __builtin_bit_cast(int, __floats2half2_rn(yB[0], yB[1]));
        w.w = __builtin_bit_cast(int, __floats2half2_rn(yB[2], yB[3]));
        ybA[buf][ty * ZP + zp] = w;
        ybB[buf][ty * ZP + zp] = __builtin_bit_cast(unsigned, __floats2half2_rn(yA[4], yB[4]));
    };

    // ---- x-window state ----
    float acc = 0.f;
    float sA[5], sB[5];
    unsigned hp[4][5];          // history: half2(SA[q], SB[q]) per step
    #pragma unroll
    for (int q = 0; q < 5; ++q) { sA[q] = 0.f; sB[q] = 0.f; }
    #pragma unroll
    for (int k = 0; k < 4; ++k)
        #pragma unroll
        for (int q = 0; q < 5; ++q) hp[k][q] = 0u;

    auto s2win = [&](int buf, int i) {   // stage2 (z-box) from ybuf[buf] + x-window for slice i
        const int base = ty * ZP;
        int4 p0 = ybA[buf][base + (zp == 0      ? 0      : zp - 1)];
        int4 p1 = ybA[buf][base + zp];
        int4 p2 = ybA[buf][base + (zp == ZP - 1 ? ZP - 1 : zp + 1)];
        unsigned b0 = ybB[buf][base + (zp == 0      ? 0      : zp - 1)];
        unsigned b2 = ybB[buf][base + (zp == ZP - 1 ? ZP - 1 : zp + 1)];
        const unsigned b1 = ybB[buf][base + zp];
        if (zp == 0)      { p0.z = p0.x; p0.w = p0.y; b0 = (b0 & 0xffffu) | (b0 << 16); }
        if (zp == ZP - 1) { p2.x = p2.z; p2.y = p2.w; b2 = (b2 >> 16) | (b2 & 0xffff0000u); }

        const __half2 t0  = __hadd2(__hadd2(h2(p0.z), h2(p1.x)), __hadd2(h2(p1.z), h2(p2.x)));
        const __half2 A01 = __hadd2(t0, h2(p0.x));
        const __half2 B01 = __hadd2(t0, h2(p2.z));
        const __half2 t1  = __hadd2(__hadd2(h2(p0.w), h2(p1.y)), __hadd2(h2(p1.w), h2(p2.y)));
        const __half2 A23 = __hadd2(t1, h2(p0.y));
        const __half2 B23 = __hadd2(t1, h2(p2.w));
        const __half2 c0 = h2((int)b0), c1 = h2((int)b1), c2 = h2((int)b2);
        const float tb = __high2float(c0) + __low2float(c1) + __high2float(c1) + __low2float(c2);
        const float SA[5] = { __low2float(A01), __high2float(A01),
                              __low2float(A23), __high2float(A23),
                              tb + __low2float(c0) };
        const float SB[5] = { __low2float(B01), __high2float(B01),
                              __low2float(B23), __high2float(B23),
                              tb + __high2float(c2) };

        #pragma unroll
        for (int q = 0; q < 5; ++q) { sA[q] += SA[q]; sB[q] += SB[q]; }
        if (i >= 4) {
            const float inv = 1.0f / 125.0f;
            {
                const float cross = sA[2] - sA[0] * sA[1] * inv;
                const float fvar  = sA[3] - sA[0] * sA[0] * inv;
                const float mvar  = sA[4] - sA[1] * sA[1] * inv;
                acc += cross * cross / (fvar * mvar + 0.1f);
            }
            {
                const float cross = sB[2] - sB[0] * sB[1] * inv;
                const float fvar  = sB[3] - sB[0] * sB[0] * inv;
                const float mvar  = sB[4] - sB[1] * sB[1] * inv;
                acc += cross * cross / (fvar * mvar + 0.1f);
            }
            #pragma unroll
            for (int q = 0; q < 5; ++q) {
                const __half2 v = h2((int)hp[0][q]);
                sA[q] -= __low2float(v);
                sB[q] -= __high2float(v);
            }
        }
        #pragma unroll
        for (int k = 0; k < 3; ++k)
            #pragma unroll
            for (int q = 0; q < 5; ++q) hp[k][q] = hp[k + 1][q];
        #pragma unroll
        for (int q = 0; q < 5; ++q)
            hp[3][q] = __builtin_bit_cast(unsigned, __floats2half2_rn(SA[q], SB[q]));
    };

    // ---- prologue: slices 0,1 ----
    float pfA[4], pmA[4], pfB[4], pmB[4];
    issueR(0, pfA, pmA);
    issueR(1, pfB, pmB);
    writeW(0, pfA, pmA);
    writeW(1, pfB, pmB);
    __syncthreads();

    // ---- paired main loop: iteration t = slices (2t, 2t+1) ----
    for (int t = 0; t < NPAIR; ++t) {
        const int s0 = 2 * t;
        if (t + 1 < NPAIR) {               // prefetch next pair (full-region cover)
            issueR(s0 + 2, pfA, pmA);
            issueR(s0 + 3, pfB, pmB);
        }
        stage1(0);                          // slice s0   (independent chains,
        stage1(1);                          // slice s0+1  compiler interleaves)
        __syncthreads();                    // ybuf[0..1] visible; rawS reads done
        s2win(0, s0);
        s2win(1, s0 + 1);
        if (t + 1 < NPAIR) {
            writeW(0, pfA, pmA);            // rawS readers passed barrier above
            writeW(1, pfB, pmB);
            __syncthreads();                // rawS ready; ybuf reads done
        }
    }

    // ---- reduction: wave shuffle (no barrier) + tiny LDS combine ----
    #pragma unroll
    for (int off = 32; off > 0; off >>= 1) acc += __shfl_down(acc, off, 64);
    if ((tid & 63) == 0) wred[tid >> 6] = acc;
    __syncthreads();
    if (tid == 0) {
        float a = 0.f;
        #pragma unroll
        for (int w = 0; w < NT / 64; ++w) a += wred[w];
        partials[blockIdx.y * NXB + blockIdx.x] = a;
    }
}

// ---------------------------------------------------------------------------
// Final deterministic reduction, writes -sum.
// ---------------------------------------------------------------------------
__global__ __launch_bounds__(256) void lcc_finalize(const float* __restrict__ partials,
                                                    int n, float* __restrict__ out) {
    __shared__ float red[256];
    float a = 0.f;
    for (int i = threadIdx.x; i < n; i += 256) a += partials[i];
    red[threadIdx.x] = a;
    __syncthreads();
    #pragma unroll
    for (int st = 128; st > 0; st >>= 1) {
        if (threadIdx.x < st) red[threadIdx.x] += red[threadIdx.x + st];
        __syncthreads();
    }
    if (threadIdx.x == 0) out[0] = -red[0];
}

// ---------------------------------------------------------------------------
// Fallback: direct 125-tap (only if ws is tiny).
// ---------------------------------------------------------------------------
__global__ __launch_bounds__(256) void lcc_direct(const float* __restrict__ f,
                                                  const float* __restrict__ m,
                                                  float* __restrict__ partials) {
    float acc = 0.f;
    for (int idx = blockIdx.x * 256 + threadIdx.x; idx < NVOX; idx += 256 * gridDim.x) {
        const int z = idx % DZ;
        const int y = (idx / DZ) % DY;
        const int x = idx / PLANE;
        float sf = 0, sm = 0, sfm = 0, sff = 0, smm = 0;
        for (int dx = -2; dx <= 2; ++dx) {
            const int xx = iclamp(x + dx, DX - 1);
            for (int dy = -2; dy <= 2; ++dy) {
                const int yy = iclamp(y + dy, DY - 1);
                const size_t b = (size_t)xx * PLANE + (size_t)yy * DZ;
                #pragma unroll
                for (int dz = -2; dz <= 2; ++dz) {
                    const int zz = iclamp(z + dz, DZ - 1);
                    const float fv = f[b + zz], mv = m[b + zz];
                    sf += fv; sm += mv; sfm += fv * mv; sff += fv * fv; smm += mv * mv;
                }
            }
        }
        const float inv = 1.0f / 125.0f;
        const float cross = sfm - sf * sm * inv;
        const float fvar  = sff - sf * sf * inv;
        const float mvar  = smm - sm * sm * inv;
        acc += cross * cross / (fvar * mvar + 0.1f);
    }
    __shared__ float red[256];
    red[threadIdx.x] = acc;
    __syncthreads();
    #pragma unroll
    for (int st = 128; st > 0; st >>= 1) {
        if (threadIdx.x < st) red[threadIdx.x] += red[threadIdx.x + st];
        __syncthreads();
    }
    if (threadIdx.x == 0) partials[blockIdx.x] = red[0];
}

extern "C" void kernel_launch(void* const* d_in, const int* in_sizes, int n_in,
                              void* d_out, int out_size, void* d_ws, size_t ws_size,
                              hipStream_t stream) {
    const float* f = (const float*)d_in[0];
    const float* m = (const float*)d_in[1];
    float* out = (float*)d_out;

    if (ws_size >= NBLK * sizeof(float)) {
        float* partials = (float*)d_ws;
        lcc_fused<<<dim3(NXB, NYB), NT, 0, stream>>>(f, m, partials);
        lcc_finalize<<<1, 256, 0, stream>>>(partials, NBLK, out);
    } else {
        const int nb = 512;
        float* partials = (float*)d_ws;
        lcc_direct<<<nb, 256, 0, stream>>>(f, m, partials);
        lcc_finalize<<<1, 256, 0, stream>>>(partials, nb, out);
    }
}